// Round 4
// baseline (415.473 us; speedup 1.0000x reference)
//
#include <hip/hip_runtime.h>
#include <stdint.h>

#define FH 64
#define FW 64
#define CIN 1536
#define C3C 512
#define C4C 1024
#define COUT 512
#define BATCH 16
#define NPIX 4096
#define NBOX 10
#define MPAD 256   // 10 boxes * 25 bins = 250, padded
#define KT128 12   // CIN/128 K-tiles

typedef float v4f __attribute__((ext_vector_type(4)));

#define GLOAD_LDS16(g, l) __builtin_amdgcn_global_load_lds( \
    (const __attribute__((address_space(1))) void*)(g),     \
    (__attribute__((address_space(3))) void*)(l), 16, 0, 0)

#define BARRIER() asm volatile("s_barrier" ::: "memory")

// pack 4 floats -> 4 fp8 e4m3 bytes in one u32 (byte k = f[k])
__device__ __forceinline__ uint32_t pack4_fp8(float a, float b, float c, float d) {
    int lo = __builtin_amdgcn_cvt_pk_fp8_f32(a, b, 0, false);
    int v  = __builtin_amdgcn_cvt_pk_fp8_f32(c, d, lo, true);
    return (uint32_t)v;
}
__device__ __forceinline__ unsigned char f32_to_fp8(float a) {
    return (unsigned char)(__builtin_amdgcn_cvt_pk_fp8_f32(a, a, 0, false) & 0xff);
}

// ---------------- BN constant folding (W was scaled x16 -> scale/16) -------
__global__ void prep_bn(const float* __restrict__ bng, const float* __restrict__ bnb,
                        const float* __restrict__ bnm, const float* __restrict__ bnv,
                        const float* __restrict__ bconv,
                        float* __restrict__ scale, float* __restrict__ shift) {
    int o = threadIdx.x;
    if (o < COUT) {
        float inv = bng[o] / sqrtf(bnv[o] + 1e-5f);
        scale[o] = inv * 0.0625f;             // /16: W quantized as W*16
        shift[o] = bnb[o] + inv * (bconv[o] - bnm[o]);
    }
}

// ---------------- W f32 -> fp8 (x16) ---------------------------------------
__global__ void conv_w(const float* __restrict__ w, uint32_t* __restrict__ w8, int n4) {
    int i = blockIdx.x * 256 + threadIdx.x;
    if (i < n4) {
        float4 f = *(const float4*)(w + i * 4);
        w8[i] = pack4_fp8(f.x * 16.0f, f.y * 16.0f, f.z * 16.0f, f.w * 16.0f);
    }
}

// ---------------- build fusedT[b][pix][c] fp8 (K-major) --------------------
// tile: 128 channels x 64 px (one y row). LDS u32 = 4 packed channels.
// c4 path: float2 loads + cross-lane shuffles (was VMEM-issue-bound).
// LDS chunk XOR-swizzled by (px>>1)&7 (write was 8-way conflicted).
__global__ __launch_bounds__(256) void build_fusedT(const float* __restrict__ c3,
                                                    const float* __restrict__ c4,
                                                    unsigned char* __restrict__ fusedT) {
    __shared__ uint32_t lds[64 * 36];
    int ct = blockIdx.x;          // 0..11; <4 -> c3, else c4
    int y  = blockIdx.y;
    int b  = blockIdx.z;
    int t  = threadIdx.x;
    int pg = t & 15;              // pixel quad: px 4pg..4pg+3
    int cq = t >> 4;              // 0..15; cquad = cq + 16r

    #pragma unroll
    for (int r = 0; r < 2; ++r) {
        int cquad = cq + 16 * r;
        float vv[4][4];           // [channel][pixel]
        if (ct < 4) {
            int ch = ct * 128 + 4 * cquad;
            const float* src = c3 + (((size_t)(b * C3C + ch) * FH + y) * FW) + 4 * pg;
            #pragma unroll
            for (int k = 0; k < 4; ++k) {
                float4 f = *(const float4*)(src + (size_t)k * (FH * FW));
                vv[k][0] = f.x; vv[k][1] = f.y; vv[k][2] = f.z; vv[k][3] = f.w;
            }
        } else {
            int ch = ct * 128 - 512 + 4 * cquad;
            int jy = y >> 1;
            int jyB = min(max(jy + ((y & 1) ? 1 : -1), 0), 31);
            const float* base = c4 + (size_t)(b * C4C + ch) * 1024;
            #pragma unroll
            for (int k = 0; k < 4; ++k) {
                const float* pc = base + (size_t)k * 1024;
                float2 f0 = *(const float2*)(pc + jy * 32 + 2 * pg);
                float2 f1 = *(const float2*)(pc + jyB * 32 + 2 * pg);
                float rbA = 0.75f * f0.x + 0.25f * f1.x;   // rb[2pg]
                float rbB = 0.75f * f0.y + 0.25f * f1.y;   // rb[2pg+1]
                float rbm = __shfl_up(rbB, 1, 16);          // rb[2pg-1]
                float rbp = __shfl_down(rbA, 1, 16);        // rb[2pg+2]
                if (pg == 0)  rbm = rbA;                    // km clamp
                if (pg == 15) rbp = rbB;                    // kp clamp
                vv[k][0] = 0.75f * rbA + 0.25f * rbm;
                vv[k][1] = 0.75f * rbA + 0.25f * rbB;
                vv[k][2] = 0.75f * rbB + 0.25f * rbA;
                vv[k][3] = 0.75f * rbB + 0.25f * rbp;
            }
        }
        #pragma unroll
        for (int i = 0; i < 4; ++i) {
            int px = 4 * pg + i;
            lds[px * 36 + 4 * ((cquad >> 2) ^ ((px >> 1) & 7)) + (cquad & 3)] =
                pack4_fp8(vv[0][i], vv[1][i], vv[2][i], vv[3][i]);
        }
    }
    __syncthreads();
    // write: 64 px x 128 B; thread covers 2 x 16 B
    int g = t & 7;                 // 16-channel group
    #pragma unroll
    for (int rr = 0; rr < 2; ++rr) {
        int px = (t >> 3) + 32 * rr;
        uint4 w = *(const uint4*)(&lds[px * 36 + 4 * (g ^ ((px >> 1) & 7))]);
        *(uint4*)(fusedT + ((size_t)b * NPIX + y * FW + px) * CIN + ct * 128 + g * 16) = w;
    }
}

// ---------------- fp8 GEMM + BN + ReLU, 256x256 tile, BK=128, 2-phase ------
// Barrier amortization: BK=128 (128 KB LDS, free since occupancy is
// reg-bound at 1 block/CU), 2 phases/tile x 64 MFMA per barrier-pair
// (was 4 phases x 16 -> 8 barriers/tile costing ~38% of the kernel).
// Counted vmcnt: S1={A0,A2,B0..B3} (needed ph1), S2={A1,A3} (ph2);
// issue S1(kt+1) in ph1(kt), S2(kt+1) in ph2(kt);
// vmcnt(6) end-ph1 (drains S2(kt)), vmcnt(2) end-ph2 (drains S1(kt+1)).
// Swizzle: chunk c of row r stored at position c^(r&7); staged by
// sourcing chunk (t&7)^((t>>3)&7); read at ((2s+q2)^(l16&7))*16+q1.
// 4 words/bank on read = wave64-b64 structural minimum.
__global__ __launch_bounds__(512, 2) void gemm_bn_relu(
        const unsigned char* __restrict__ w8,
        const unsigned char* __restrict__ fusedT,
        const float* __restrict__ scale, const float* __restrict__ shift,
        unsigned char* __restrict__ attr) {
    __shared__ __align__(16) unsigned char lds_a[2][32768];
    __shared__ __align__(16) unsigned char lds_b[2][32768];
    const int t  = threadIdx.x;
    const int n0 = blockIdx.x * 256;   // pixel tile
    const int o0 = blockIdx.y * 256;   // out-channel tile
    const int b  = blockIdx.z;
    const int wave = t >> 6, lane = t & 63;
    const int wm = wave & 1, wn = wave >> 1;   // 2 x 4 wave grid
    const int quad = lane >> 4, l16 = lane & 15;
    const int q2 = quad >> 1, q1 = (quad & 1) * 8;
    int cs[4];
    #pragma unroll
    for (int s = 0; s < 4; ++s) cs[s] = (((2 * s + q2) ^ (l16 & 7)) * 16) + q1;
    const unsigned char* fb = fusedT + (size_t)b * NPIX * CIN;

    // ---- staging: 512 threads cover one 64row x 128B unit ----
    const int rr = t >> 3;                        // row within unit (0..63)
    const int cg = (t & 7) ^ (rr & 7);            // inverse-swizzled src chunk
    const unsigned char* gA = w8 + (size_t)(o0 + rr) * CIN + cg * 16;
    const unsigned char* gB = fb + (size_t)(n0 + rr) * CIN + cg * 16;

#define SA(u, kt, d) GLOAD_LDS16(gA + (size_t)(u) * (64 * CIN) + (kt) * 128, \
                                 &lds_a[d][(u) * 8192 + t * 16])
#define SB(u, kt, d) GLOAD_LDS16(gB + (size_t)(u) * (64 * CIN) + (kt) * 128, \
                                 &lds_b[d][(u) * 8192 + t * 16])
#define RA(d, ph, i, s) (*(const long*)(&lds_a[d][((wm * 128 + (ph) * 64 + (i) * 16 + l16) << 7) + cs[s]]))
#define RB(d, j, s)     (*(const long*)(&lds_b[d][((wn * 64 + (j) * 16 + l16) << 7) + cs[s]]))

    v4f acc[8][4];   // [ph*4+i][j]
    #pragma unroll
    for (int i = 0; i < 8; ++i)
        #pragma unroll
        for (int j = 0; j < 4; ++j) acc[i][j] = (v4f)0.0f;

    // ---- prologue: tile0 full (8 units) + S1(tile1) (6 units) ----
    SA(0, 0, 0); SA(1, 0, 0); SA(2, 0, 0); SA(3, 0, 0);
    SB(0, 0, 0); SB(1, 0, 0); SB(2, 0, 0); SB(3, 0, 0);
    SA(0, 1, 1); SA(2, 1, 1); SB(0, 1, 1); SB(1, 1, 1); SB(2, 1, 1); SB(3, 1, 1);
    asm volatile("s_waitcnt vmcnt(6)" ::: "memory");
    BARRIER();

    long af[4][4], bf[4][4];

    for (int kt = 0; kt < KT128; ++kt) {
        const int cur = kt & 1, nxt = cur ^ 1;

        // ---- phase 1: rows wm*128..+64, all 4 col-blocks ----
        #pragma unroll
        for (int i = 0; i < 4; ++i)
            #pragma unroll
            for (int s = 0; s < 4; ++s) af[i][s] = RA(cur, 0, i, s);
        #pragma unroll
        for (int j = 0; j < 4; ++j)
            #pragma unroll
            for (int s = 0; s < 4; ++s) bf[j][s] = RB(cur, j, s);
        if (kt > 0 && kt + 1 < KT128) {
            SA(0, kt + 1, nxt); SA(2, kt + 1, nxt);
            SB(0, kt + 1, nxt); SB(1, kt + 1, nxt);
            SB(2, kt + 1, nxt); SB(3, kt + 1, nxt);
        }
        BARRIER();
        __builtin_amdgcn_s_setprio(1);
        #pragma unroll
        for (int s = 0; s < 4; ++s)
            #pragma unroll
            for (int i = 0; i < 4; ++i)
                #pragma unroll
                for (int j = 0; j < 4; ++j)
                    acc[i][j] = __builtin_amdgcn_mfma_f32_16x16x32_fp8_fp8(af[i][s], bf[j][s], acc[i][j], 0, 0, 0);
        __builtin_amdgcn_s_setprio(0);
        if (kt + 1 < KT128) { asm volatile("s_waitcnt vmcnt(6)" ::: "memory"); }
        else               { asm volatile("s_waitcnt vmcnt(0)" ::: "memory"); }
        BARRIER();

        // ---- phase 2: rows wm*128+64..+128 (B frags reused) ----
        #pragma unroll
        for (int i = 0; i < 4; ++i)
            #pragma unroll
            for (int s = 0; s < 4; ++s) af[i][s] = RA(cur, 1, i, s);
        if (kt + 1 < KT128) { SA(1, kt + 1, nxt); SA(3, kt + 1, nxt); }
        BARRIER();
        __builtin_amdgcn_s_setprio(1);
        #pragma unroll
        for (int s = 0; s < 4; ++s)
            #pragma unroll
            for (int i = 0; i < 4; ++i)
                #pragma unroll
                for (int j = 0; j < 4; ++j)
                    acc[4 + i][j] = __builtin_amdgcn_mfma_f32_16x16x32_fp8_fp8(af[i][s], bf[j][s], acc[4 + i][j], 0, 0, 0);
        __builtin_amdgcn_s_setprio(0);
        if (kt + 1 < KT128) { asm volatile("s_waitcnt vmcnt(2)" ::: "memory"); }
        BARRIER();
    }

    // ---- epilogue: BN + ReLU + fp8 channel-major store ----
    unsigned char* ab = attr + (size_t)b * COUT * NPIX;
    #pragma unroll
    for (int a = 0; a < 8; ++a) {
        int obase = o0 + wm * 128 + (a >> 2) * 64 + (a & 3) * 16 + quad * 4;
        #pragma unroll
        for (int r = 0; r < 4; ++r) {
            int oo = obase + r;
            float sc = scale[oo], sh = shift[oo];
            #pragma unroll
            for (int j = 0; j < 4; ++j) {
                int n = n0 + wn * 64 + j * 16 + l16;
                float v = fmaxf(acc[a][j][r] * sc + sh, 0.0f);
                ab[(size_t)oo * NPIX + n] = f32_to_fp8(v);
            }
        }
    }
#undef SA
#undef SB
#undef RA
#undef RB
}

// ---------------- build pooling matrix P[b][m][pix] fp8 (x64) --------------
__global__ __launch_bounds__(256) void build_P(const float* __restrict__ boxes,
                                               unsigned char* __restrict__ P) {
    int br  = blockIdx.x;                // 0..159
    int m25 = blockIdx.y;                // 0..24
    int b   = br / NBOX;
    int m   = (br % NBOX) * 25 + m25;
    int p   = m25 / 5, q = m25 % 5;
    int t   = threadIdx.x;
    int y   = t >> 2;
    int x0  = (t & 3) * 16;
    const float* bx = boxes + (size_t)br * 4;
    int x1 = min(max((int)floorf(bx[0] * 0.125f), 0), 63);
    int y1 = min(max((int)floorf(bx[1] * 0.125f), 0), 63);
    int x2 = min(max((int)ceilf (bx[2] * 0.125f), 0), 63);
    int y2 = min(max((int)ceilf (bx[3] * 0.125f), 0), 63);
    if (x2 <= x1) x2 = min(x1 + 1, 64);
    if (y2 <= y1) y2 = min(y1 + 1, 64);
    int Lx = x2 - x1, Ly = y2 - y1;
    int sx = x1 + (q * Lx) / 5;
    int ex = x1 + ((q + 1) * Lx + 4) / 5;
    int sy = y1 + (p * Ly) / 5;
    int ey = y1 + ((p + 1) * Ly + 4) / 5;
    float wyv  = (y >= sy && y < ey) ? 1.0f / (float)(ey - sy) : 0.0f;
    float pval = 64.0f * wyv / (float)(ex - sx);
    float v[16];
    #pragma unroll
    for (int i = 0; i < 16; ++i) {
        int xi = x0 + i;
        v[i] = (xi >= sx && xi < ex) ? pval : 0.0f;
    }
    uint4 w;
    w.x = pack4_fp8(v[0],  v[1],  v[2],  v[3]);
    w.y = pack4_fp8(v[4],  v[5],  v[6],  v[7]);
    w.z = pack4_fp8(v[8],  v[9],  v[10], v[11]);
    w.w = pack4_fp8(v[12], v[13], v[14], v[15]);
    *(uint4*)(P + ((size_t)b * MPAD + m) * NPIX + y * FW + x0) = w;
}

// ---------------- fp8 pool GEMM, K-split x4, dense partials ----------------
__global__ __launch_bounds__(256) void pool_gemm(
        const unsigned char* __restrict__ P,
        const unsigned char* __restrict__ attr,
        float* __restrict__ part2) {
    __shared__ __align__(16) unsigned char lds_a[128 * 64];
    __shared__ __align__(16) unsigned char lds_b[128 * 64];
    int t  = threadIdx.x;
    int m0 = blockIdx.x * 128;
    int c0 = (blockIdx.y & 3) * 128;
    int seg = blockIdx.y >> 2;
    int b  = blockIdx.z;
    int wave = t >> 6, lane = t & 63;
    int wm = wave & 1, wn = wave >> 1;
    int quad = lane >> 4, l16 = lane & 15;
    const unsigned char* Pb = P + (size_t)b * MPAD * NPIX + seg * 1024;
    const unsigned char* ab = attr + (size_t)b * COUT * NPIX + seg * 1024;

    v4f acc[4][4];
    #pragma unroll
    for (int i = 0; i < 4; ++i)
        #pragma unroll
        for (int j = 0; j < 4; ++j) acc[i][j] = (v4f)0.0f;

    int row = t >> 2;
    int cg  = (t & 3) ^ ((row >> 1) & 3);
    const unsigned char* ga0 = Pb + (size_t)(m0 + row) * NPIX + cg * 16;
    const unsigned char* ga1 = Pb + (size_t)(m0 + row + 64) * NPIX + cg * 16;
    const unsigned char* gb0 = ab + (size_t)(c0 + row) * NPIX + cg * 16;
    const unsigned char* gb1 = ab + (size_t)(c0 + row + 64) * NPIX + cg * 16;
    unsigned char* la0 = lds_a + t * 16;
    unsigned char* la1 = lds_a + 4096 + t * 16;
    unsigned char* lb0 = lds_b + t * 16;
    unsigned char* lb1 = lds_b + 4096 + t * 16;

    int ra[4], rb[4];
    #pragma unroll
    for (int i = 0; i < 4; ++i) { ra[i] = wm * 64 + i * 16 + l16; rb[i] = wn * 64 + i * 16 + l16; }
    int q2 = quad >> 1, q1 = (quad & 1) * 8;

    for (int kt = 0; kt < 1024 / 64; ++kt) {
        __syncthreads();
        GLOAD_LDS16(ga0, la0);
        GLOAD_LDS16(ga1, la1);
        GLOAD_LDS16(gb0, lb0);
        GLOAD_LDS16(gb1, lb1);
        ga0 += 64; ga1 += 64; gb0 += 64; gb1 += 64;
        __syncthreads();

        #pragma unroll
        for (int s = 0; s < 2; ++s) {
            long af[4], bf[4];
            #pragma unroll
            for (int i = 0; i < 4; ++i) {
                int pa = (2 * s + q2) ^ ((ra[i] >> 1) & 3);
                af[i] = *(const long*)(lds_a + ra[i] * 64 + pa * 16 + q1);
                int pb = (2 * s + q2) ^ ((rb[i] >> 1) & 3);
                bf[i] = *(const long*)(lds_b + rb[i] * 64 + pb * 16 + q1);
            }
            #pragma unroll
            for (int i = 0; i < 4; ++i)
                #pragma unroll
                for (int j = 0; j < 4; ++j)
                    acc[i][j] = __builtin_amdgcn_mfma_f32_16x16x32_fp8_fp8(af[i], bf[j], acc[i][j], 0, 0, 0);
        }
    }

    float* pp = part2 + (((size_t)seg * BATCH + b) * MPAD) * COUT;
    #pragma unroll
    for (int i = 0; i < 4; ++i) {
        #pragma unroll
        for (int r = 0; r < 4; ++r) {
            int mrow = m0 + wm * 64 + i * 16 + quad * 4 + r;
            #pragma unroll
            for (int j = 0; j < 4; ++j) {
                int c = c0 + wn * 64 + j * 16 + l16;
                pp[(size_t)mrow * COUT + c] = acc[i][j][r];
            }
        }
    }
}

// ---------------- reduce 4 segs (/64 for P scaling), transpose to out ------
__global__ __launch_bounds__(256) void pool_reduce(const float* __restrict__ part2,
                                                   float* __restrict__ out) {
    const size_t SEG = (size_t)BATCH * MPAD * COUT;
    int i = blockIdx.x * 256 + threadIdx.x;
    int c = i & (COUT - 1);
    int m = (i >> 9) & (MPAD - 1);
    int b = i >> 17;
    if (m >= 250) return;
    float s = part2[i] + part2[i + SEG] + part2[i + 2 * SEG] + part2[i + 3 * SEG];
    int box = m / 25, bin = m - box * 25;
    out[640 + ((size_t)(b * NBOX + box) * COUT + c) * 25 + bin] = s * 0.015625f;
}

extern "C" void kernel_launch(void* const* d_in, const int* in_sizes, int n_in,
                              void* d_out, int out_size, void* d_ws, size_t ws_size,
                              hipStream_t stream) {
    const float* c3     = (const float*)d_in[0];
    const float* c4     = (const float*)d_in[1];
    const float* boxes  = (const float*)d_in[2];
    const float* w_conv = (const float*)d_in[3];
    const float* b_conv = (const float*)d_in[4];
    const float* bng    = (const float*)d_in[5];
    const float* bnb    = (const float*)d_in[6];
    const float* bnm    = (const float*)d_in[7];
    const float* bnv    = (const float*)d_in[8];
    float* out = (float*)d_out;

    char* ws = (char*)d_ws;
    // fp8 layout (no aliasing needed):
    unsigned char* fusedT = (unsigned char*)ws;                 // 100663296 B
    unsigned char* P      = (unsigned char*)(ws + 100663296);   //  16777216 B
    float*         part2  = (float*)(ws + 117440512);           //  33554432 B
    unsigned char* w8     = (unsigned char*)(ws + 150994944);   //    786432 B
    float*         scale  = (float*)(ws + 151781376);           //      2048 B
    float*         shift  = (float*)(ws + 151783424);           //      2048 B
    unsigned char* attr   = (unsigned char*)(ws + 151785472);   //  33554432 B

    hipMemcpyAsync(d_out, d_in[2], 640 * sizeof(float), hipMemcpyDeviceToDevice, stream);
    prep_bn<<<1, 512, 0, stream>>>(bng, bnb, bnm, bnv, b_conv, scale, shift);
    conv_w<<<(COUT * CIN / 4 + 255) / 256, 256, 0, stream>>>(w_conv, (uint32_t*)w8, COUT * CIN / 4);
    build_P<<<dim3(160, 25), 256, 0, stream>>>(boxes, P);
    build_fusedT<<<dim3(12, 64, 16), 256, 0, stream>>>(c3, c4, fusedT);
    gemm_bn_relu<<<dim3(16, 2, 16), 512, 0, stream>>>(w8, fusedT, scale, shift, attr);
    pool_gemm<<<dim3(2, 16, 16), 256, 0, stream>>>(P, attr, part2);
    pool_reduce<<<(BATCH * MPAD * COUT) / 256, 256, 0, stream>>>(part2, out);
    (void)in_sizes; (void)n_in; (void)out_size; (void)ws_size;
}

// Round 5
// 395.015 us; speedup vs baseline: 1.0518x; 1.0518x over previous
//
#include <hip/hip_runtime.h>
#include <stdint.h>

#define FH 64
#define FW 64
#define CIN 1536
#define C3C 512
#define C4C 1024
#define COUT 512
#define BATCH 16
#define NPIX 4096
#define NBOX 10
#define MPAD 256   // 10 boxes * 25 bins = 250, padded
#define KT128 12   // CIN/128 K-tiles

typedef float v4f __attribute__((ext_vector_type(4)));
typedef long  v2l __attribute__((ext_vector_type(2)));

#define GLOAD_LDS16(g, l) __builtin_amdgcn_global_load_lds( \
    (const __attribute__((address_space(1))) void*)(g),     \
    (__attribute__((address_space(3))) void*)(l), 16, 0, 0)

#define BARRIER() asm volatile("s_barrier" ::: "memory")

// pack 4 floats -> 4 fp8 e4m3 bytes in one u32 (byte k = f[k])
__device__ __forceinline__ uint32_t pack4_fp8(float a, float b, float c, float d) {
    int lo = __builtin_amdgcn_cvt_pk_fp8_f32(a, b, 0, false);
    int v  = __builtin_amdgcn_cvt_pk_fp8_f32(c, d, lo, true);
    return (uint32_t)v;
}
__device__ __forceinline__ unsigned char f32_to_fp8(float a) {
    return (unsigned char)(__builtin_amdgcn_cvt_pk_fp8_f32(a, a, 0, false) & 0xff);
}

// K-permutation within each 128-byte K-block of w8/fusedT:
// logical k7 stored at byte quad*32 + s*8 + b  (quad=(k7>>3)&3, s=k7>>5, b=k7&7).
// Makes each lane's MFMA operand pair {s,s+1} 16 contiguous bytes -> ds_read_b128.
// Applied identically to BOTH operands, so sum_k A[m][k]B[n][k] is preserved.

// ---------------- BN constant folding (W was scaled x16 -> scale/16) -------
__global__ void prep_bn(const float* __restrict__ bng, const float* __restrict__ bnb,
                        const float* __restrict__ bnm, const float* __restrict__ bnv,
                        const float* __restrict__ bconv,
                        float* __restrict__ scale, float* __restrict__ shift) {
    int o = threadIdx.x;
    if (o < COUT) {
        float inv = bng[o] / sqrtf(bnv[o] + 1e-5f);
        scale[o] = inv * 0.0625f;             // /16: W quantized as W*16
        shift[o] = bnb[o] + inv * (bconv[o] - bnm[o]);
    }
}

// ---------------- W f32 -> fp8 (x16), k-permuted layout --------------------
__global__ void conv_w(const float* __restrict__ w, unsigned char* __restrict__ w8, int n4) {
    int i = blockIdx.x * 256 + threadIdx.x;
    if (i < n4) {
        float4 f = *(const float4*)(w + i * 4);
        uint32_t v = pack4_fp8(f.x * 16.0f, f.y * 16.0f, f.z * 16.0f, f.w * 16.0f);
        int c0 = (i * 4) % CIN;
        int o  = (i * 4) / CIN;
        int k7 = c0 & 127;
        int pos = ((k7 >> 3) & 3) * 32 + (k7 >> 5) * 8 + (k7 & 7);
        *(uint32_t*)(w8 + (size_t)o * CIN + (c0 & ~127) + pos) = v;
    }
}

// ---------------- build fusedT[b][pix][c] fp8 (K-major, k-permuted) --------
// tile: 128 channels x 64 px (one y row). LDS u32 = 4 packed channels.
// c4 path: float2 loads + cross-lane shuffles (was VMEM-issue-bound).
// LDS chunk XOR-swizzled by (px>>1)&7 (write was 8-way conflicted).
// Global write: each logical 16-B chunk g splits into two 8-B stores at the
// k-permuted positions.
__global__ __launch_bounds__(256) void build_fusedT(const float* __restrict__ c3,
                                                    const float* __restrict__ c4,
                                                    unsigned char* __restrict__ fusedT) {
    __shared__ uint32_t lds[64 * 36];
    int ct = blockIdx.x;          // 0..11; <4 -> c3, else c4
    int y  = blockIdx.y;
    int b  = blockIdx.z;
    int t  = threadIdx.x;
    int pg = t & 15;              // pixel quad: px 4pg..4pg+3
    int cq = t >> 4;              // 0..15; cquad = cq + 16r

    #pragma unroll
    for (int r = 0; r < 2; ++r) {
        int cquad = cq + 16 * r;
        float vv[4][4];           // [channel][pixel]
        if (ct < 4) {
            int ch = ct * 128 + 4 * cquad;
            const float* src = c3 + (((size_t)(b * C3C + ch) * FH + y) * FW) + 4 * pg;
            #pragma unroll
            for (int k = 0; k < 4; ++k) {
                float4 f = *(const float4*)(src + (size_t)k * (FH * FW));
                vv[k][0] = f.x; vv[k][1] = f.y; vv[k][2] = f.z; vv[k][3] = f.w;
            }
        } else {
            int ch = ct * 128 - 512 + 4 * cquad;
            int jy = y >> 1;
            int jyB = min(max(jy + ((y & 1) ? 1 : -1), 0), 31);
            const float* base = c4 + (size_t)(b * C4C + ch) * 1024;
            #pragma unroll
            for (int k = 0; k < 4; ++k) {
                const float* pc = base + (size_t)k * 1024;
                float2 f0 = *(const float2*)(pc + jy * 32 + 2 * pg);
                float2 f1 = *(const float2*)(pc + jyB * 32 + 2 * pg);
                float rbA = 0.75f * f0.x + 0.25f * f1.x;   // rb[2pg]
                float rbB = 0.75f * f0.y + 0.25f * f1.y;   // rb[2pg+1]
                float rbm = __shfl_up(rbB, 1, 16);          // rb[2pg-1]
                float rbp = __shfl_down(rbA, 1, 16);        // rb[2pg+2]
                if (pg == 0)  rbm = rbA;                    // km clamp
                if (pg == 15) rbp = rbB;                    // kp clamp
                vv[k][0] = 0.75f * rbA + 0.25f * rbm;
                vv[k][1] = 0.75f * rbA + 0.25f * rbB;
                vv[k][2] = 0.75f * rbB + 0.25f * rbA;
                vv[k][3] = 0.75f * rbB + 0.25f * rbp;
            }
        }
        #pragma unroll
        for (int i = 0; i < 4; ++i) {
            int px = 4 * pg + i;
            lds[px * 36 + 4 * ((cquad >> 2) ^ ((px >> 1) & 7)) + (cquad & 3)] =
                pack4_fp8(vv[0][i], vv[1][i], vv[2][i], vv[3][i]);
        }
    }
    __syncthreads();
    // write: 64 px x 128 B; thread covers one 16-B logical chunk as 2x8B
    int g = t & 7;                 // 16-channel group
    #pragma unroll
    for (int rr2 = 0; rr2 < 2; ++rr2) {
        int px = (t >> 3) + 32 * rr2;
        uint4 w = *(const uint4*)(&lds[px * 36 + 4 * (g ^ ((px >> 1) & 7))]);
        unsigned char* dst = fusedT + ((size_t)b * NPIX + y * FW + px) * CIN + ct * 128;
        // channels 16g..16g+7 -> quad=(2g)&3, s=g>>1 ; +8..15 -> quad=(2g+1)&3
        int pos0 = ((2 * g) & 3) * 32 + (g >> 1) * 8;
        int pos1 = ((2 * g + 1) & 3) * 32 + (g >> 1) * 8;
        *(uint2*)(dst + pos0) = make_uint2(w.x, w.y);
        *(uint2*)(dst + pos1) = make_uint2(w.z, w.w);
    }
}

// ---------------- fp8 GEMM + BN + ReLU, 256x256 tile, BK=128, 2-phase ------
// LDS-read-bound fix (R4 post-mortem): k-permuted operands make each
// fragment pair one ds_read_b128 (24/K-tile/wave vs 48 b64), with chunk
// swizzle c^(row&7) -> exactly 2 lanes per 16-B slot = 8 words/bank
// uniform = conflict-free b128 floor. Mid-phase barrier removed so
// waves' ds_reads overlap other waves' MFMAs (per-phase vmcnt+barrier
// pairs retained: S1={A0,A2,B0..3} drains end-ph2, S2={A1,A3} end-ph1).
__global__ __launch_bounds__(512, 2) void gemm_bn_relu(
        const unsigned char* __restrict__ w8,
        const unsigned char* __restrict__ fusedT,
        const float* __restrict__ scale, const float* __restrict__ shift,
        unsigned char* __restrict__ attr) {
    __shared__ __align__(16) unsigned char lds_a[2][32768];
    __shared__ __align__(16) unsigned char lds_b[2][32768];
    const int t  = threadIdx.x;
    const int n0 = blockIdx.x * 256;   // pixel tile
    const int o0 = blockIdx.y * 256;   // out-channel tile
    const int b  = blockIdx.z;
    const int wave = t >> 6, lane = t & 63;
    const int wm = wave & 1, wn = wave >> 1;   // 2 x 4 wave grid
    const int quad = lane >> 4, l16 = lane & 15;
    // b128 chunk offsets: chunk c = quad*2+h stored at (c ^ (row&7)); row&7 = l16&7
    const int cp0 = (((quad << 1) ^ (l16 & 7)) << 4);
    const int cp1 = cp0 ^ 16;
    const unsigned char* fb = fusedT + (size_t)b * NPIX * CIN;

    // ---- staging: 512 threads cover one 64row x 128B unit ----
    const int rr = t >> 3;                        // row within unit (0..63)
    const int cg = (t & 7) ^ (rr & 7);            // inverse-swizzled src chunk
    const unsigned char* gA = w8 + (size_t)(o0 + rr) * CIN + cg * 16;
    const unsigned char* gB = fb + (size_t)(n0 + rr) * CIN + cg * 16;

#define SA(u, kt, d) GLOAD_LDS16(gA + (size_t)(u) * (64 * CIN) + (kt) * 128, \
                                 &lds_a[d][(u) * 8192 + t * 16])
#define SB(u, kt, d) GLOAD_LDS16(gB + (size_t)(u) * (64 * CIN) + (kt) * 128, \
                                 &lds_b[d][(u) * 8192 + t * 16])
#define RAV(d, ph, i, cp) (*(const v2l*)(&lds_a[d][((wm * 128 + (ph) * 64 + (i) * 16 + l16) << 7) + (cp)]))
#define RBV(d, j, cp)     (*(const v2l*)(&lds_b[d][((wn * 64 + (j) * 16 + l16) << 7) + (cp)]))

    v4f acc[8][4];   // [ph*4+i][j]
    #pragma unroll
    for (int i = 0; i < 8; ++i)
        #pragma unroll
        for (int j = 0; j < 4; ++j) acc[i][j] = (v4f)0.0f;

    // ---- prologue: tile0 full (8 units) + S1(tile1) (6 units) ----
    SA(0, 0, 0); SA(1, 0, 0); SA(2, 0, 0); SA(3, 0, 0);
    SB(0, 0, 0); SB(1, 0, 0); SB(2, 0, 0); SB(3, 0, 0);
    SA(0, 1, 1); SA(2, 1, 1); SB(0, 1, 1); SB(1, 1, 1); SB(2, 1, 1); SB(3, 1, 1);
    asm volatile("s_waitcnt vmcnt(6)" ::: "memory");
    BARRIER();

    v2l ah0[4], ah1[4], bh0[4], bh1[4];

    for (int kt = 0; kt < KT128; ++kt) {
        const int cur = kt & 1, nxt = cur ^ 1;

        // ---- phase 1: A rows wm*128..+64 x all B ----
        #pragma unroll
        for (int i = 0; i < 4; ++i) { ah0[i] = RAV(cur, 0, i, cp0); ah1[i] = RAV(cur, 0, i, cp1); }
        #pragma unroll
        for (int j = 0; j < 4; ++j) { bh0[j] = RBV(cur, j, cp0); bh1[j] = RBV(cur, j, cp1); }
        if (kt > 0 && kt + 1 < KT128) {
            SA(0, kt + 1, nxt); SA(2, kt + 1, nxt);
            SB(0, kt + 1, nxt); SB(1, kt + 1, nxt);
            SB(2, kt + 1, nxt); SB(3, kt + 1, nxt);
        }
        __builtin_amdgcn_s_setprio(1);
        #pragma unroll
        for (int s = 0; s < 2; ++s)
            #pragma unroll
            for (int i = 0; i < 4; ++i)
                #pragma unroll
                for (int j = 0; j < 4; ++j)
                    acc[i][j] = __builtin_amdgcn_mfma_f32_16x16x32_fp8_fp8(ah0[i][s], bh0[j][s], acc[i][j], 0, 0, 0);
        #pragma unroll
        for (int s = 0; s < 2; ++s)
            #pragma unroll
            for (int i = 0; i < 4; ++i)
                #pragma unroll
                for (int j = 0; j < 4; ++j)
                    acc[i][j] = __builtin_amdgcn_mfma_f32_16x16x32_fp8_fp8(ah1[i][s], bh1[j][s], acc[i][j], 0, 0, 0);
        __builtin_amdgcn_s_setprio(0);
        if (kt + 1 < KT128) { asm volatile("s_waitcnt vmcnt(6)" ::: "memory"); }
        else               { asm volatile("s_waitcnt vmcnt(0)" ::: "memory"); }
        BARRIER();

        // ---- phase 2: A rows wm*128+64..+128 (B frags reused) ----
        #pragma unroll
        for (int i = 0; i < 4; ++i) { ah0[i] = RAV(cur, 1, i, cp0); ah1[i] = RAV(cur, 1, i, cp1); }
        if (kt + 1 < KT128) { SA(1, kt + 1, nxt); SA(3, kt + 1, nxt); }
        __builtin_amdgcn_s_setprio(1);
        #pragma unroll
        for (int s = 0; s < 2; ++s)
            #pragma unroll
            for (int i = 0; i < 4; ++i)
                #pragma unroll
                for (int j = 0; j < 4; ++j)
                    acc[4 + i][j] = __builtin_amdgcn_mfma_f32_16x16x32_fp8_fp8(ah0[i][s], bh0[j][s], acc[4 + i][j], 0, 0, 0);
        #pragma unroll
        for (int s = 0; s < 2; ++s)
            #pragma unroll
            for (int i = 0; i < 4; ++i)
                #pragma unroll
                for (int j = 0; j < 4; ++j)
                    acc[4 + i][j] = __builtin_amdgcn_mfma_f32_16x16x32_fp8_fp8(ah1[i][s], bh1[j][s], acc[4 + i][j], 0, 0, 0);
        __builtin_amdgcn_s_setprio(0);
        if (kt + 1 < KT128) { asm volatile("s_waitcnt vmcnt(2)" ::: "memory"); }
        BARRIER();
    }

    // ---- epilogue: BN + ReLU + fp8 channel-major store ----
    unsigned char* ab = attr + (size_t)b * COUT * NPIX;
    #pragma unroll
    for (int a = 0; a < 8; ++a) {
        int obase = o0 + wm * 128 + (a >> 2) * 64 + (a & 3) * 16 + quad * 4;
        #pragma unroll
        for (int r = 0; r < 4; ++r) {
            int oo = obase + r;
            float sc = scale[oo], sh = shift[oo];
            #pragma unroll
            for (int j = 0; j < 4; ++j) {
                int n = n0 + wn * 64 + j * 16 + l16;
                float v = fmaxf(acc[a][j][r] * sc + sh, 0.0f);
                ab[(size_t)oo * NPIX + n] = f32_to_fp8(v);
            }
        }
    }
#undef SA
#undef SB
#undef RAV
#undef RBV
}

// ---------------- build pooling matrix P[b][m][pix] fp8 (x64) --------------
__global__ __launch_bounds__(256) void build_P(const float* __restrict__ boxes,
                                               unsigned char* __restrict__ P) {
    int br  = blockIdx.x;                // 0..159
    int m25 = blockIdx.y;                // 0..24
    int b   = br / NBOX;
    int m   = (br % NBOX) * 25 + m25;
    int p   = m25 / 5, q = m25 % 5;
    int t   = threadIdx.x;
    int y   = t >> 2;
    int x0  = (t & 3) * 16;
    const float* bx = boxes + (size_t)br * 4;
    int x1 = min(max((int)floorf(bx[0] * 0.125f), 0), 63);
    int y1 = min(max((int)floorf(bx[1] * 0.125f), 0), 63);
    int x2 = min(max((int)ceilf (bx[2] * 0.125f), 0), 63);
    int y2 = min(max((int)ceilf (bx[3] * 0.125f), 0), 63);
    if (x2 <= x1) x2 = min(x1 + 1, 64);
    if (y2 <= y1) y2 = min(y1 + 1, 64);
    int Lx = x2 - x1, Ly = y2 - y1;
    int sx = x1 + (q * Lx) / 5;
    int ex = x1 + ((q + 1) * Lx + 4) / 5;
    int sy = y1 + (p * Ly) / 5;
    int ey = y1 + ((p + 1) * Ly + 4) / 5;
    float wyv  = (y >= sy && y < ey) ? 1.0f / (float)(ey - sy) : 0.0f;
    float pval = 64.0f * wyv / (float)(ex - sx);
    float v[16];
    #pragma unroll
    for (int i = 0; i < 16; ++i) {
        int xi = x0 + i;
        v[i] = (xi >= sx && xi < ex) ? pval : 0.0f;
    }
    uint4 w;
    w.x = pack4_fp8(v[0],  v[1],  v[2],  v[3]);
    w.y = pack4_fp8(v[4],  v[5],  v[6],  v[7]);
    w.z = pack4_fp8(v[8],  v[9],  v[10], v[11]);
    w.w = pack4_fp8(v[12], v[13], v[14], v[15]);
    *(uint4*)(P + ((size_t)b * MPAD + m) * NPIX + y * FW + x0) = w;
}

// ---------------- fp8 pool GEMM, K-split x4, dense partials ----------------
__global__ __launch_bounds__(256) void pool_gemm(
        const unsigned char* __restrict__ P,
        const unsigned char* __restrict__ attr,
        float* __restrict__ part2) {
    __shared__ __align__(16) unsigned char lds_a[128 * 64];
    __shared__ __align__(16) unsigned char lds_b[128 * 64];
    int t  = threadIdx.x;
    int m0 = blockIdx.x * 128;
    int c0 = (blockIdx.y & 3) * 128;
    int seg = blockIdx.y >> 2;
    int b  = blockIdx.z;
    int wave = t >> 6, lane = t & 63;
    int wm = wave & 1, wn = wave >> 1;
    int quad = lane >> 4, l16 = lane & 15;
    const unsigned char* Pb = P + (size_t)b * MPAD * NPIX + seg * 1024;
    const unsigned char* ab = attr + (size_t)b * COUT * NPIX + seg * 1024;

    v4f acc[4][4];
    #pragma unroll
    for (int i = 0; i < 4; ++i)
        #pragma unroll
        for (int j = 0; j < 4; ++j) acc[i][j] = (v4f)0.0f;

    int row = t >> 2;
    int cg  = (t & 3) ^ ((row >> 1) & 3);
    const unsigned char* ga0 = Pb + (size_t)(m0 + row) * NPIX + cg * 16;
    const unsigned char* ga1 = Pb + (size_t)(m0 + row + 64) * NPIX + cg * 16;
    const unsigned char* gb0 = ab + (size_t)(c0 + row) * NPIX + cg * 16;
    const unsigned char* gb1 = ab + (size_t)(c0 + row + 64) * NPIX + cg * 16;
    unsigned char* la0 = lds_a + t * 16;
    unsigned char* la1 = lds_a + 4096 + t * 16;
    unsigned char* lb0 = lds_b + t * 16;
    unsigned char* lb1 = lds_b + 4096 + t * 16;

    int ra[4], rb[4];
    #pragma unroll
    for (int i = 0; i < 4; ++i) { ra[i] = wm * 64 + i * 16 + l16; rb[i] = wn * 64 + i * 16 + l16; }
    int q2 = quad >> 1, q1 = (quad & 1) * 8;

    for (int kt = 0; kt < 1024 / 64; ++kt) {
        __syncthreads();
        GLOAD_LDS16(ga0, la0);
        GLOAD_LDS16(ga1, la1);
        GLOAD_LDS16(gb0, lb0);
        GLOAD_LDS16(gb1, lb1);
        ga0 += 64; ga1 += 64; gb0 += 64; gb1 += 64;
        __syncthreads();

        #pragma unroll
        for (int s = 0; s < 2; ++s) {
            long af[4], bf[4];
            #pragma unroll
            for (int i = 0; i < 4; ++i) {
                int pa = (2 * s + q2) ^ ((ra[i] >> 1) & 3);
                af[i] = *(const long*)(lds_a + ra[i] * 64 + pa * 16 + q1);
                int pb = (2 * s + q2) ^ ((rb[i] >> 1) & 3);
                bf[i] = *(const long*)(lds_b + rb[i] * 64 + pb * 16 + q1);
            }
            #pragma unroll
            for (int i = 0; i < 4; ++i)
                #pragma unroll
                for (int j = 0; j < 4; ++j)
                    acc[i][j] = __builtin_amdgcn_mfma_f32_16x16x32_fp8_fp8(af[i], bf[j], acc[i][j], 0, 0, 0);
        }
    }

    float* pp = part2 + (((size_t)seg * BATCH + b) * MPAD) * COUT;
    #pragma unroll
    for (int i = 0; i < 4; ++i) {
        #pragma unroll
        for (int r = 0; r < 4; ++r) {
            int mrow = m0 + wm * 64 + i * 16 + quad * 4 + r;
            #pragma unroll
            for (int j = 0; j < 4; ++j) {
                int c = c0 + wn * 64 + j * 16 + l16;
                pp[(size_t)mrow * COUT + c] = acc[i][j][r];
            }
        }
    }
}

// ---------------- reduce 4 segs (/64 for P scaling), transpose to out ------
__global__ __launch_bounds__(256) void pool_reduce(const float* __restrict__ part2,
                                                   float* __restrict__ out) {
    const size_t SEG = (size_t)BATCH * MPAD * COUT;
    int i = blockIdx.x * 256 + threadIdx.x;
    int c = i & (COUT - 1);
    int m = (i >> 9) & (MPAD - 1);
    int b = i >> 17;
    if (m >= 250) return;
    float s = part2[i] + part2[i + SEG] + part2[i + 2 * SEG] + part2[i + 3 * SEG];
    int box = m / 25, bin = m - box * 25;
    out[640 + ((size_t)(b * NBOX + box) * COUT + c) * 25 + bin] = s * 0.015625f;
}

extern "C" void kernel_launch(void* const* d_in, const int* in_sizes, int n_in,
                              void* d_out, int out_size, void* d_ws, size_t ws_size,
                              hipStream_t stream) {
    const float* c3     = (const float*)d_in[0];
    const float* c4     = (const float*)d_in[1];
    const float* boxes  = (const float*)d_in[2];
    const float* w_conv = (const float*)d_in[3];
    const float* b_conv = (const float*)d_in[4];
    const float* bng    = (const float*)d_in[5];
    const float* bnb    = (const float*)d_in[6];
    const float* bnm    = (const float*)d_in[7];
    const float* bnv    = (const float*)d_in[8];
    float* out = (float*)d_out;

    char* ws = (char*)d_ws;
    // fp8 layout (no aliasing needed):
    unsigned char* fusedT = (unsigned char*)ws;                 // 100663296 B
    unsigned char* P      = (unsigned char*)(ws + 100663296);   //  16777216 B
    float*         part2  = (float*)(ws + 117440512);           //  33554432 B
    unsigned char* w8     = (unsigned char*)(ws + 150994944);   //    786432 B
    float*         scale  = (float*)(ws + 151781376);           //      2048 B
    float*         shift  = (float*)(ws + 151783424);           //      2048 B
    unsigned char* attr   = (unsigned char*)(ws + 151785472);   //  33554432 B

    hipMemcpyAsync(d_out, d_in[2], 640 * sizeof(float), hipMemcpyDeviceToDevice, stream);
    prep_bn<<<1, 512, 0, stream>>>(bng, bnb, bnm, bnv, b_conv, scale, shift);
    conv_w<<<(COUT * CIN / 4 + 255) / 256, 256, 0, stream>>>(w_conv, w8, COUT * CIN / 4);
    build_P<<<dim3(160, 25), 256, 0, stream>>>(boxes, P);
    build_fusedT<<<dim3(12, 64, 16), 256, 0, stream>>>(c3, c4, fusedT);
    gemm_bn_relu<<<dim3(16, 2, 16), 512, 0, stream>>>(w8, fusedT, scale, shift, attr);
    pool_gemm<<<dim3(2, 16, 16), 256, 0, stream>>>(P, attr, part2);
    pool_reduce<<<(BATCH * MPAD * COUT) / 256, 256, 0, stream>>>(part2, out);
    (void)in_sizes; (void)n_in; (void)out_size; (void)ws_size;
}